// Round 7
// baseline (246.140 us; speedup 1.0000x reference)
//
#include <hip/hip_runtime.h>

#define B_ 2
#define S_ 2048
#define H_ 16
#define D_ 64

typedef _Float16 f16;
typedef _Float16 f16x8 __attribute__((ext_vector_type(8)));
typedef float f32x4 __attribute__((ext_vector_type(4)));
typedef float f32x16 __attribute__((ext_vector_type(16)));

#define LOG2E 1.44269504088896f

__device__ inline unsigned int pk16(float a, float b) {
    return __builtin_bit_cast(unsigned int, __builtin_amdgcn_cvt_pkrtz(a, b));
}

__device__ inline f16x8 cvt8(const float* p) {
    float4 u = *(const float4*)p, v = *(const float4*)(p + 4);
    f16x8 r;
    r[0] = (f16)u.x; r[1] = (f16)u.y; r[2] = (f16)u.z; r[3] = (f16)u.w;
    r[4] = (f16)v.x; r[5] = (f16)v.y; r[6] = (f16)v.z; r[7] = (f16)v.w;
    return r;
}

// ---------------- projection kernel (MFMA 16x16x32) ----------------
// grid = (S/64, B*H, 3), block = 256 (4 waves; wave w owns 16 tokens of one head)
// q out: [B,H,S,D] f16, pre-scaled by 0.125*log2(e)  (log2-domain softmax)
// k out: [B,H,S,D] f16
// v out: [B,H,D,S] f16  (transposed directly, scatter stores)
__global__ __launch_bounds__(256) void proj_kernel(
    const float* __restrict__ query, const float* __restrict__ key,
    const float* __restrict__ value,
    const float* __restrict__ Wq, const float* __restrict__ bq,
    const float* __restrict__ Wk, const float* __restrict__ bk,
    const float* __restrict__ Wv, const float* __restrict__ bv,
    f16* __restrict__ qo, f16* __restrict__ ko, f16* __restrict__ vto)
{
    const int which = blockIdx.z;
    const float* x    = which == 0 ? query : (which == 1 ? key : value);
    const float* W    = which == 0 ? Wq    : (which == 1 ? Wk  : Wv);
    const float* bias = which == 0 ? bq    : (which == 1 ? bk  : bv);
    const float scale = which == 0 ? 0.125f * LOG2E : 1.0f;

    const int bh = blockIdx.y;          // b*H + h
    const int b  = bh >> 4, h = bh & 15;
    const int s0 = blockIdx.x * 64;

    const int t = threadIdx.x;
    const int wave = t >> 6, lane = t & 63;
    const int lg = lane >> 4, lr = lane & 15;

    const float* xrow = x + ((long)((b * S_ + s0 + wave * 16 + lr)) * H_ + h) * 64;
    f16x8 a[2];
    a[0] = cvt8(xrow + 0 * 32 + lg * 8);
    a[1] = cvt8(xrow + 1 * 32 + lg * 8);

    f32x4 acc[4] = {};
    #pragma unroll
    for (int jb = 0; jb < 4; ++jb) {
        #pragma unroll
        for (int kc = 0; kc < 2; ++kc) {
            f16x8 bf = cvt8(W + (jb * 16 + lr) * 64 + kc * 32 + lg * 8);
            acc[jb] = __builtin_amdgcn_mfma_f32_16x16x32_f16(a[kc], bf, acc[jb], 0, 0, 0);
        }
    }

    if (which == 2) {
        // V^T scatter store: [bh][d][s]
        #pragma unroll
        for (int jb = 0; jb < 4; ++jb) {
            float bj = bias[jb * 16 + lr];
            int d = jb * 16 + lr;
            #pragma unroll
            for (int r = 0; r < 4; ++r) {
                int s = s0 + wave * 16 + lg * 4 + r;
                vto[((long)bh * 64 + d) * S_ + s] = (f16)(acc[jb][r] + bj);
            }
        }
    } else {
        f16* out = which == 0 ? qo : ko;
        const long orow = (long)bh * S_ + s0 + wave * 16;
        #pragma unroll
        for (int jb = 0; jb < 4; ++jb) {
            float bj = bias[jb * 16 + lr];
            #pragma unroll
            for (int r = 0; r < 4; ++r) {
                out[(orow + lg * 4 + r) * 64 + jb * 16 + lr] =
                    (f16)((acc[jb][r] + bj) * scale);
            }
        }
    }
}

// ---------------- flash attention, 32x32 swapped-QK, no LDS ----------------
// grid = 512 (bh = bid&31 for XCD/L2 locality, qt = bid>>5), block = 256
// (4 warps x 32 q-rows = 128 q-rows/block; 32 K-tiles of 64 keys)
__global__ __launch_bounds__(256) void attn_kernel(
    const f16* __restrict__ Qg, const f16* __restrict__ Kg,
    const f16* __restrict__ Vtg, float* __restrict__ Og)
{
    const int bid = blockIdx.x;
    const int bh = bid & 31;
    const int qt = bid >> 5;
    const int warp = threadIdx.x >> 6;
    const int lane = threadIdx.x & 63;
    const int hi = lane >> 5;
    const int lq = lane & 31;
    const int q0 = qt * 128 + warp * 32;

    const f16* Qb = Qg  + ((long)bh * S_ + q0) * 64;
    const f16* Kb = Kg  + (long)bh * S_ * 64;
    const f16* Vt = Vtg + (long)bh * 64 * S_;

    // Q^T B-operand fragments: col=q=lq, k=d = ks*16 + hi*8 + e
    f16x8 qf[4];
    #pragma unroll
    for (int ks = 0; ks < 4; ++ks)
        qf[ks] = *(const f16x8*)(Qb + (long)lq * 64 + ks * 16 + hi * 8);

    f32x16 o0 = {}, o1 = {};   // O^T: col=q=lq, row d = db*32 + (r&3)+8*(r>>2)+4*hi
    float m = -1e30f, l = 0.f;

    for (int kt = 0; kt < S_ / 64; ++kt) {
        const f16* Kt = Kb + kt * 64 * 64;
        const f16* Vk = Vt + kt * 64;

        // ---- QK^T swapped: s[kb] = K_rows(kb) x Q^T  (S^T[key][q]) ----
        f32x16 s0 = {}, s1 = {};
        #pragma unroll
        for (int ks = 0; ks < 4; ++ks) {
            f16x8 k0 = *(const f16x8*)(Kt + (lq)      * 64 + ks * 16 + hi * 8);
            f16x8 k1 = *(const f16x8*)(Kt + (32 + lq) * 64 + ks * 16 + hi * 8);
            __builtin_amdgcn_s_setprio(1);
            s0 = __builtin_amdgcn_mfma_f32_32x32x16_f16(k0, qf[ks], s0, 0, 0, 0);
            s1 = __builtin_amdgcn_mfma_f32_32x32x16_f16(k1, qf[ks], s1, 0, 0, 0);
            __builtin_amdgcn_s_setprio(0);
        }

        // ---- V^T loads issued early (latency hides under softmax) ----
        f16x8 vf[8];
        #pragma unroll
        for (int db = 0; db < 2; ++db)
            #pragma unroll
            for (int ks = 0; ks < 4; ++ks)
                vf[db * 4 + ks] = *(const f16x8*)(Vk + (long)(db * 32 + lq) * S_ + ks * 16 + hi * 8);

        // ---- online softmax (log2 domain), lane-local rows ----
        float pm = s0[0];
        #pragma unroll
        for (int r = 1; r < 16; ++r) pm = fmaxf(pm, s0[r]);
        #pragma unroll
        for (int r = 0; r < 16; ++r) pm = fmaxf(pm, s1[r]);
        pm = fmaxf(pm, __shfl_xor(pm, 32));

        if (!__all(pm <= m + 10.0f)) {      // defer-max: skip rescale when no growth
            float mn = fmaxf(m, pm);
            float rs = exp2f(m - mn);
            #pragma unroll
            for (int r = 0; r < 16; ++r) { o0[r] *= rs; o1[r] *= rs; }
            l *= rs;
            m = mn;
        }

        float sum = 0.f;
        #pragma unroll
        for (int r = 0; r < 16; ++r) { s0[r] = exp2f(s0[r] - m); sum += s0[r]; }
        #pragma unroll
        for (int r = 0; r < 16; ++r) { s1[r] = exp2f(s1[r] - m); sum += s1[r]; }
        l += sum;

        // ---- pack P to f16 pairs, redistribute across hi-halves ----
        unsigned int w[16], xw[16];
        #pragma unroll
        for (int i = 0; i < 8; ++i) {
            w[i]     = pk16(s0[2 * i], s0[2 * i + 1]);
            w[8 + i] = pk16(s1[2 * i], s1[2 * i + 1]);
        }
        #pragma unroll
        for (int i = 0; i < 16; ++i) xw[i] = __shfl_xor(w[i], 32);

        union PA { unsigned int u[4]; f16x8 v; };
        PA pa[4];
        #pragma unroll
        for (int ks = 0; ks < 4; ++ks) {
            int bse = (ks >> 1) * 8 + (ks & 1) * 4;
            pa[ks].u[0] = hi ? xw[bse + 2] : w[bse + 0];
            pa[ks].u[1] = hi ? xw[bse + 3] : w[bse + 1];
            pa[ks].u[2] = hi ? w[bse + 2]  : xw[bse + 0];
            pa[ks].u[3] = hi ? w[bse + 3]  : xw[bse + 1];
        }

        // ---- PV: O^T += V^T x P^T ----
        __builtin_amdgcn_s_setprio(1);
        #pragma unroll
        for (int ks = 0; ks < 4; ++ks) {
            o0 = __builtin_amdgcn_mfma_f32_32x32x16_f16(vf[ks],     pa[ks].v, o0, 0, 0, 0);
            o1 = __builtin_amdgcn_mfma_f32_32x32x16_f16(vf[4 + ks], pa[ks].v, o1, 0, 0, 0);
        }
        __builtin_amdgcn_s_setprio(0);
    }

    // ---- epilogue ----
    float lt = l + __shfl_xor(l, 32);
    float inv = 1.0f / lt;
    float* orow = Og + ((long)bh * S_ + q0 + lq) * 64;
    #pragma unroll
    for (int r = 0; r < 16; ++r) {
        int d0 = (r & 3) + 8 * (r >> 2) + 4 * hi;
        orow[d0]      = o0[r] * inv;
        orow[d0 + 32] = o1[r] * inv;
    }
}

extern "C" void kernel_launch(void* const* d_in, const int* in_sizes, int n_in,
                              void* d_out, int out_size, void* d_ws, size_t ws_size,
                              hipStream_t stream) {
    const float* query = (const float*)d_in[0];
    const float* key   = (const float*)d_in[1];
    const float* value = (const float*)d_in[2];
    const float* Wq    = (const float*)d_in[3];
    const float* bq    = (const float*)d_in[4];
    const float* Wk    = (const float*)d_in[5];
    const float* bk    = (const float*)d_in[6];
    const float* Wv    = (const float*)d_in[7];
    const float* bv    = (const float*)d_in[8];

    const size_t elems = (size_t)B_ * H_ * S_ * D_;
    f16* qws  = (f16*)d_ws;
    f16* kws  = qws + elems;
    f16* vtws = kws + elems;   // [B,H,D,S]

    proj_kernel<<<dim3(S_ / 64, B_ * H_, 3), 256, 0, stream>>>(
        query, key, value, Wq, bq, Wk, bk, Wv, bv, qws, kws, vtws);

    attn_kernel<<<512, 256, 0, stream>>>(qws, kws, vtws, (float*)d_out);
}

// Round 8
// 201.185 us; speedup vs baseline: 1.2235x; 1.2235x over previous
//
#include <hip/hip_runtime.h>

#define B_ 2
#define S_ 2048
#define H_ 16
#define D_ 64

typedef _Float16 f16;
typedef _Float16 f16x8 __attribute__((ext_vector_type(8)));
typedef float f32x4 __attribute__((ext_vector_type(4)));
typedef float f32x16 __attribute__((ext_vector_type(16)));

#define LOG2E 1.44269504088896f

__device__ inline unsigned int pk16(float a, float b) {
    return __builtin_bit_cast(unsigned int, __builtin_amdgcn_cvt_pkrtz(a, b));
}

__device__ inline f16x8 cvt8(const float* p) {
    float4 u = *(const float4*)p, v = *(const float4*)(p + 4);
    f16x8 r;
    r[0] = (f16)u.x; r[1] = (f16)u.y; r[2] = (f16)u.z; r[3] = (f16)u.w;
    r[4] = (f16)v.x; r[5] = (f16)v.y; r[6] = (f16)v.z; r[7] = (f16)v.w;
    return r;
}

// async global->LDS, 16B per lane; LDS dest = wave-uniform base + lane*16
__device__ inline void ldst16(const void* g, void* l) {
    __builtin_amdgcn_global_load_lds(
        (const __attribute__((address_space(1))) unsigned int*)g,
        (__attribute__((address_space(3))) unsigned int*)l, 16, 0, 0);
}

// swizzled LDS fragment read: 128B rows, slot XOR (row&7)
__device__ inline f16x8 lds_frag(const f16* base, int row, int colByte) {
    int byte = (row * 128 + colByte) ^ ((row & 7) << 4);
    return *(const f16x8*)((const char*)base + byte);
}

// ---------------- projection kernel (MFMA 16x16x32) ----------------
// grid = (S/64, B*H, 3), block = 256.
// q: [B,H,S,D] f16 scaled by 0.125*log2e; k: [B,H,S,D]; v: [B,H,D,S] (V^T).
__global__ __launch_bounds__(256) void proj_kernel(
    const float* __restrict__ query, const float* __restrict__ key,
    const float* __restrict__ value,
    const float* __restrict__ Wq, const float* __restrict__ bq,
    const float* __restrict__ Wk, const float* __restrict__ bk,
    const float* __restrict__ Wv, const float* __restrict__ bv,
    f16* __restrict__ qo, f16* __restrict__ ko, f16* __restrict__ vto)
{
    const int which = blockIdx.z;
    const float* x    = which == 0 ? query : (which == 1 ? key : value);
    const float* W    = which == 0 ? Wq    : (which == 1 ? Wk  : Wv);
    const float* bias = which == 0 ? bq    : (which == 1 ? bk  : bv);
    const float scale = which == 0 ? 0.125f * LOG2E : 1.0f;

    const int bh = blockIdx.y;
    const int b  = bh >> 4, h = bh & 15;
    const int s0 = blockIdx.x * 64;

    const int t = threadIdx.x;
    const int wave = t >> 6, lane = t & 63;
    const int lg = lane >> 4, lr = lane & 15;

    const float* xrow = x + ((long)((b * S_ + s0 + wave * 16 + lr)) * H_ + h) * 64;
    f16x8 a[2];
    a[0] = cvt8(xrow + 0 * 32 + lg * 8);
    a[1] = cvt8(xrow + 1 * 32 + lg * 8);

    f32x4 acc[4] = {};
    if (which == 2) {
        // swapped: C rows = d_out, cols = tokens -> contiguous V^T stores
        #pragma unroll
        for (int jb = 0; jb < 4; ++jb) {
            #pragma unroll
            for (int kc = 0; kc < 2; ++kc) {
                f16x8 bf = cvt8(W + (jb * 16 + lr) * 64 + kc * 32 + lg * 8);
                acc[jb] = __builtin_amdgcn_mfma_f32_16x16x32_f16(bf, a[kc], acc[jb], 0, 0, 0);
            }
        }
        #pragma unroll
        for (int jb = 0; jb < 4; ++jb) {
            float4 bj4 = *(const float4*)(bias + jb * 16 + lg * 4);
            #pragma unroll
            for (int r = 0; r < 4; ++r) {
                int d = jb * 16 + lg * 4 + r;
                float bj = r == 0 ? bj4.x : (r == 1 ? bj4.y : (r == 2 ? bj4.z : bj4.w));
                vto[((long)bh * 64 + d) * S_ + s0 + wave * 16 + lr] = (f16)(acc[jb][r] + bj);
            }
        }
    } else {
        #pragma unroll
        for (int jb = 0; jb < 4; ++jb) {
            #pragma unroll
            for (int kc = 0; kc < 2; ++kc) {
                f16x8 bf = cvt8(W + (jb * 16 + lr) * 64 + kc * 32 + lg * 8);
                acc[jb] = __builtin_amdgcn_mfma_f32_16x16x32_f16(a[kc], bf, acc[jb], 0, 0, 0);
            }
        }
        f16* out = which == 0 ? qo : ko;
        const long orow = (long)bh * S_ + s0 + wave * 16;
        #pragma unroll
        for (int jb = 0; jb < 4; ++jb) {
            float bj = bias[jb * 16 + lr];
            #pragma unroll
            for (int r = 0; r < 4; ++r) {
                out[(orow + lg * 4 + r) * 64 + jb * 16 + lr] =
                    (f16)((acc[jb][r] + bj) * scale);
            }
        }
    }
}

// ---------------- flash attention: swapped 32x32, LDS-staged, 2-phase ----------------
// grid = 512 (bh = bid&31), block = 256 (4 warps x 32 q)
__global__ __launch_bounds__(256) void attn_kernel(
    const f16* __restrict__ Qg, const f16* __restrict__ Kg,
    const f16* __restrict__ Vtg, float* __restrict__ Og)
{
    __shared__ f16 Klds[2][64 * 64];   // [key][d], swizzled slots
    __shared__ f16 Vlds[2][64 * 64];   // [d][key], swizzled slots

    const int bid = blockIdx.x;
    const int bh = bid & 31;
    const int qt = bid >> 5;
    const int warp = threadIdx.x >> 6;
    const int lane = threadIdx.x & 63;
    const int hi = lane >> 5;
    const int lq = lane & 31;
    const int q0 = qt * 128 + warp * 32;

    const f16* Qb = Qg  + ((long)bh * S_ + q0) * 64;
    const f16* Kb = Kg  + (long)bh * S_ * 64;
    const f16* Vt = Vtg + (long)bh * 64 * S_;

    const int rIn = lane >> 3, cs = lane & 7;   // staging: row-in-chunk, 16B slot

    // Q^T B-operand fragments
    f16x8 qf[4];
    #pragma unroll
    for (int ks = 0; ks < 4; ++ks)
        qf[ks] = *(const f16x8*)(Qb + (long)lq * 64 + ks * 16 + hi * 8);

    f32x16 o0 = {}, o1 = {};
    float m = -1e30f, l = 0.f;

    // prologue: stage tile 0 into buf 0
    {
        const f16* Ks = Kb;
        #pragma unroll
        for (int ck = 0; ck < 2; ++ck) {
            int row = warp * 16 + ck * 8 + rIn;
            ldst16(Ks + row * 64 + (cs ^ (row & 7)) * 8,
                   &Klds[0][(warp * 16 + ck * 8) * 64]);
            int drow = warp * 16 + ck * 8 + rIn;
            ldst16(Vt + (long)drow * S_ + (cs ^ (drow & 7)) * 8,
                   &Vlds[0][(warp * 16 + ck * 8) * 64]);
        }
    }
    __syncthreads();

    for (int kt = 0; kt < S_ / 64; ++kt) {
        const int cur = kt & 1;

        // ---- issue next-tile stage (async, drains at the tile-end barrier) ----
        if (kt + 1 < S_ / 64) {
            const f16* Ks = Kb + (long)(kt + 1) * 64 * 64;
            #pragma unroll
            for (int ck = 0; ck < 2; ++ck) {
                int row = warp * 16 + ck * 8 + rIn;
                ldst16(Ks + row * 64 + (cs ^ (row & 7)) * 8,
                       &Klds[cur ^ 1][(warp * 16 + ck * 8) * 64]);
                int drow = warp * 16 + ck * 8 + rIn;
                ldst16(Vt + (long)drow * S_ + (kt + 1) * 64 + (cs ^ (drow & 7)) * 8,
                       &Vlds[cur ^ 1][(warp * 16 + ck * 8) * 64]);
            }
        }

        // ---- QK^T swapped: S^T[key][q] from LDS ----
        f32x16 s0 = {}, s1 = {};
        #pragma unroll
        for (int ks = 0; ks < 4; ++ks) {
            int cb = ks * 32 + hi * 16;
            f16x8 k0 = lds_frag(&Klds[cur][0], lq, cb);
            f16x8 k1 = lds_frag(&Klds[cur][0], 32 + lq, cb);
            __builtin_amdgcn_s_setprio(1);
            s0 = __builtin_amdgcn_mfma_f32_32x32x16_f16(k0, qf[ks], s0, 0, 0, 0);
            s1 = __builtin_amdgcn_mfma_f32_32x32x16_f16(k1, qf[ks], s1, 0, 0, 0);
            __builtin_amdgcn_s_setprio(0);
        }

        // ---- V fragments (independent of softmax; hide ds latency under VALU) ----
        f16x8 vf[8];
        #pragma unroll
        for (int db = 0; db < 2; ++db)
            #pragma unroll
            for (int ks = 0; ks < 4; ++ks)
                vf[db * 4 + ks] = lds_frag(&Vlds[cur][0], db * 32 + lq, ks * 32 + hi * 16);

        // ---- online softmax (log2 domain), lane-local; tree reductions ----
        float pm01 = fmaxf(s0[0], s0[1]), pm23 = fmaxf(s0[2], s0[3]);
        #pragma unroll
        for (int r = 4; r < 16; r += 4) {
            pm01 = fmaxf(pm01, fmaxf(s0[r], s0[r + 1]));
            pm23 = fmaxf(pm23, fmaxf(s0[r + 2], s0[r + 3]));
        }
        #pragma unroll
        for (int r = 0; r < 16; r += 4) {
            pm01 = fmaxf(pm01, fmaxf(s1[r], s1[r + 1]));
            pm23 = fmaxf(pm23, fmaxf(s1[r + 2], s1[r + 3]));
        }
        float pm = fmaxf(pm01, pm23);
        pm = fmaxf(pm, __shfl_xor(pm, 32));

        if (!__all(pm <= m + 10.0f)) {
            float mn = fmaxf(m, pm);
            float rs = exp2f(m - mn);
            #pragma unroll
            for (int r = 0; r < 16; ++r) { o0[r] *= rs; o1[r] *= rs; }
            l *= rs;
            m = mn;
        }

        float su0 = 0.f, su1 = 0.f, su2 = 0.f, su3 = 0.f;
        #pragma unroll
        for (int r = 0; r < 16; r += 4) {
            s0[r] = exp2f(s0[r] - m);     su0 += s0[r];
            s0[r + 1] = exp2f(s0[r + 1] - m); su1 += s0[r + 1];
            s0[r + 2] = exp2f(s0[r + 2] - m); su2 += s0[r + 2];
            s0[r + 3] = exp2f(s0[r + 3] - m); su3 += s0[r + 3];
        }
        #pragma unroll
        for (int r = 0; r < 16; r += 4) {
            s1[r] = exp2f(s1[r] - m);     su0 += s1[r];
            s1[r + 1] = exp2f(s1[r + 1] - m); su1 += s1[r + 1];
            s1[r + 2] = exp2f(s1[r + 2] - m); su2 += s1[r + 2];
            s1[r + 3] = exp2f(s1[r + 3] - m); su3 += s1[r + 3];
        }
        l += (su0 + su1) + (su2 + su3);

        // ---- pack P to f16, redistribute across hi-halves ----
        unsigned int w[16], xw[16];
        #pragma unroll
        for (int i = 0; i < 8; ++i) {
            w[i]     = pk16(s0[2 * i], s0[2 * i + 1]);
            w[8 + i] = pk16(s1[2 * i], s1[2 * i + 1]);
        }
        #pragma unroll
        for (int i = 0; i < 16; ++i) xw[i] = __shfl_xor(w[i], 32);

        union PA { unsigned int u[4]; f16x8 v; };
        PA pa[4];
        #pragma unroll
        for (int ks = 0; ks < 4; ++ks) {
            int bse = (ks >> 1) * 8 + (ks & 1) * 4;
            pa[ks].u[0] = hi ? xw[bse + 2] : w[bse + 0];
            pa[ks].u[1] = hi ? xw[bse + 3] : w[bse + 1];
            pa[ks].u[2] = hi ? w[bse + 2]  : xw[bse + 0];
            pa[ks].u[3] = hi ? w[bse + 3]  : xw[bse + 1];
        }

        // ---- PV: O^T += V^T x P^T ----
        __builtin_amdgcn_s_setprio(1);
        #pragma unroll
        for (int ks = 0; ks < 4; ++ks) {
            o0 = __builtin_amdgcn_mfma_f32_32x32x16_f16(vf[ks],     pa[ks].v, o0, 0, 0, 0);
            o1 = __builtin_amdgcn_mfma_f32_32x32x16_f16(vf[4 + ks], pa[ks].v, o1, 0, 0, 0);
        }
        __builtin_amdgcn_s_setprio(0);

        __syncthreads();   // drains vmcnt(0) (next tile staged) + lgkm, then barrier
    }

    // ---- epilogue ----
    float lt = l + __shfl_xor(l, 32);
    float inv = 1.0f / lt;
    float* orow = Og + ((long)bh * S_ + q0 + lq) * 64;
    #pragma unroll
    for (int r = 0; r < 16; ++r) {
        int d0 = (r & 3) + 8 * (r >> 2) + 4 * hi;
        orow[d0]      = o0[r] * inv;
        orow[d0 + 32] = o1[r] * inv;
    }
}

extern "C" void kernel_launch(void* const* d_in, const int* in_sizes, int n_in,
                              void* d_out, int out_size, void* d_ws, size_t ws_size,
                              hipStream_t stream) {
    const float* query = (const float*)d_in[0];
    const float* key   = (const float*)d_in[1];
    const float* value = (const float*)d_in[2];
    const float* Wq    = (const float*)d_in[3];
    const float* bq    = (const float*)d_in[4];
    const float* Wk    = (const float*)d_in[5];
    const float* bk    = (const float*)d_in[6];
    const float* Wv    = (const float*)d_in[7];
    const float* bv    = (const float*)d_in[8];

    const size_t elems = (size_t)B_ * H_ * S_ * D_;
    f16* qws  = (f16*)d_ws;
    f16* kws  = qws + elems;
    f16* vtws = kws + elems;   // [B,H,D,S]

    proj_kernel<<<dim3(S_ / 64, B_ * H_, 3), 256, 0, stream>>>(
        query, key, value, Wq, bq, Wk, bk, Wv, bv, qws, kws, vtws);

    attn_kernel<<<512, 256, 0, stream>>>(qws, kws, vtws, (float*)d_out);
}

// Round 9
// 191.250 us; speedup vs baseline: 1.2870x; 1.0519x over previous
//
#include <hip/hip_runtime.h>

#define B_ 2
#define S_ 2048
#define H_ 16
#define D_ 64
#define HEAD_ELEMS (64 * S_)   // 131072 f16 per head per tensor

typedef _Float16 f16;
typedef _Float16 f16x8 __attribute__((ext_vector_type(8)));
typedef float f32x4 __attribute__((ext_vector_type(4)));
typedef float f32x16 __attribute__((ext_vector_type(16)));

#define LOG2E 1.44269504088896f

__device__ inline unsigned int pk16(float a, float b) {
    return __builtin_bit_cast(unsigned int, __builtin_amdgcn_cvt_pkrtz(a, b));
}

__device__ inline f16x8 cvt8(const float* p) {
    float4 u = *(const float4*)p, v = *(const float4*)(p + 4);
    f16x8 r;
    r[0] = (f16)u.x; r[1] = (f16)u.y; r[2] = (f16)u.z; r[3] = (f16)u.w;
    r[4] = (f16)v.x; r[5] = (f16)v.y; r[6] = (f16)v.z; r[7] = (f16)v.w;
    return r;
}

// ================= projection -> fragment-linear Qf/Kf/Vf =================
// grid = (S/64, B*H, 3), block = 256.
// Output layout (per head, per 64-token tile kt): 8 fragment-groups G of
// 64 lanes x 16B, stored contiguously: elem = bh*131072 + kt*4096 + G*512 + lane*8.
//   Q,K (G = sub*4 + ks): lane(hi,lq) holds row (sub*32+lq), d-slice ks*16+hi*8..+8
//   V   (G = db*4 + ks):  lane(hi,lq) holds V^T row d=db*32+lq, s-slice ks*16+hi*8..+8
// q pre-scaled by 0.125*log2e (log2-domain softmax).
__global__ __launch_bounds__(256) void proj_kernel(
    const float* __restrict__ query, const float* __restrict__ key,
    const float* __restrict__ value,
    const float* __restrict__ Wq, const float* __restrict__ bq,
    const float* __restrict__ Wk, const float* __restrict__ bk,
    const float* __restrict__ Wv, const float* __restrict__ bv,
    f16* __restrict__ Qf, f16* __restrict__ Kf, f16* __restrict__ Vf)
{
    __shared__ char tile[8192];   // 64 rows x 128B, XOR-swizzled 16B slots

    const int which = blockIdx.z;
    const float* x    = which == 0 ? query : (which == 1 ? key : value);
    const float* W    = which == 0 ? Wq    : (which == 1 ? Wk  : Wv);
    const float* bias = which == 0 ? bq    : (which == 1 ? bk  : bv);
    const float scale = which == 0 ? 0.125f * LOG2E : 1.0f;

    const int bh = blockIdx.y;
    const int b  = bh >> 4, h = bh & 15;
    const int kt = blockIdx.x;
    const int s0 = kt * 64;

    const int t = threadIdx.x;
    const int wave = t >> 6, lane = t & 63;
    const int lg = lane >> 4, lr = lane & 15;
    const int hi = lane >> 5, lq = lane & 31;

    const float* xrow = x + ((long)((b * S_ + s0 + wave * 16 + lr)) * H_ + h) * 64;
    f16x8 a0 = cvt8(xrow + lg * 8);
    f16x8 a1 = cvt8(xrow + 32 + lg * 8);

    f32x4 acc[4] = {};
    if (which != 2) {
        // swapped: C[d][token]; lane: token = wave*16+lr, d = jb*16+lg*4+r
        #pragma unroll
        for (int jb = 0; jb < 4; ++jb) {
            f16x8 b0 = cvt8(W + (jb * 16 + lr) * 64 + lg * 8);
            f16x8 b1 = cvt8(W + (jb * 16 + lr) * 64 + 32 + lg * 8);
            acc[jb] = __builtin_amdgcn_mfma_f32_16x16x32_f16(b0, a0, acc[jb], 0, 0, 0);
            acc[jb] = __builtin_amdgcn_mfma_f32_16x16x32_f16(b1, a1, acc[jb], 0, 0, 0);
        }
        // write LDS[token][d] as packed 8B (4 consecutive d)
        #pragma unroll
        for (int jb = 0; jb < 4; ++jb) {
            float4 b4 = *(const float4*)(bias + jb * 16 + lg * 4);
            float v0 = (acc[jb][0] + b4.x) * scale;
            float v1 = (acc[jb][1] + b4.y) * scale;
            float v2 = (acc[jb][2] + b4.z) * scale;
            float v3 = (acc[jb][3] + b4.w) * scale;
            uint2 pk = { pk16(v0, v1), pk16(v2, v3) };
            int row = wave * 16 + lr;                      // token
            int byte = (row * 128 + (jb * 16 + lg * 4) * 2) ^ ((row & 7) << 4);
            *(uint2*)(tile + byte) = pk;
        }
    } else {
        // normal: C[token][d]; lane: d = jb*16+lr, tokens = wave*16+lg*4+r
        #pragma unroll
        for (int jb = 0; jb < 4; ++jb) {
            f16x8 b0 = cvt8(W + (jb * 16 + lr) * 64 + lg * 8);
            f16x8 b1 = cvt8(W + (jb * 16 + lr) * 64 + 32 + lg * 8);
            acc[jb] = __builtin_amdgcn_mfma_f32_16x16x32_f16(a0, b0, acc[jb], 0, 0, 0);
            acc[jb] = __builtin_amdgcn_mfma_f32_16x16x32_f16(a1, b1, acc[jb], 0, 0, 0);
        }
        // write LDS[d][token] (V^T) as packed 8B (4 consecutive tokens)
        #pragma unroll
        for (int jb = 0; jb < 4; ++jb) {
            float bj = bias[jb * 16 + lr];
            uint2 pk = { pk16(acc[jb][0] + bj, acc[jb][1] + bj),
                         pk16(acc[jb][2] + bj, acc[jb][3] + bj) };
            int row = jb * 16 + lr;                        // d
            int byte = (row * 128 + (wave * 16 + lg * 4) * 2) ^ ((row & 7) << 4);
            *(uint2*)(tile + byte) = pk;
        }
    }
    __syncthreads();

    // fragment-linear readout: wave w, iter i -> group G = i*4 + w
    f16* fout = which == 0 ? Qf : (which == 1 ? Kf : Vf);
    const long base = (long)bh * HEAD_ELEMS + (long)kt * 4096 + lane * 8;
    #pragma unroll
    for (int i = 0; i < 2; ++i) {
        int row = i * 32 + lq;
        int byte = (row * 128 + wave * 32 + hi * 16) ^ ((row & 7) << 4);
        f16x8 v = *(const f16x8*)(tile + byte);
        *(f16x8*)(fout + base + (i * 4 + wave) * 512) = v;
    }
}

// ============ flash attention: fragment-streaming, no LDS, no barriers ============
// grid = 512 (bh = bid&31 -> XCD/L2 locality), block = 256 (4 warps x 32 q)
__global__ __launch_bounds__(256) void attn_kernel(
    const f16* __restrict__ Qf, const f16* __restrict__ Kf,
    const f16* __restrict__ Vf, float* __restrict__ Og)
{
    const int bid = blockIdx.x;
    const int bh = bid & 31;
    const int qt = bid >> 5;
    const int warp = threadIdx.x >> 6;
    const int lane = threadIdx.x & 63;
    const int hi = lane >> 5;
    const int lq = lane & 31;
    const int q0 = qt * 128 + warp * 32;

    const f16* Qh = Qf + (long)bh * HEAD_ELEMS;
    const f16* Kh = Kf + (long)bh * HEAD_ELEMS;
    const f16* Vh = Vf + (long)bh * HEAD_ELEMS;

    // Q^T B-operand fragments (coalesced: lane*8)
    f16x8 qf[4];
    #pragma unroll
    for (int ks = 0; ks < 4; ++ks)
        qf[ks] = *(const f16x8*)(Qh + (long)qt * 8192 + warp * 2048 + ks * 512 + lane * 8);

    f32x16 o0 = {}, o1 = {};
    float m = -1e30f, l = 0.f;

    for (int kt = 0; kt < S_ / 64; ++kt) {
        const f16* Kt = Kh + (long)kt * 4096;
        const f16* Vt = Vh + (long)kt * 4096;

        // ---- K fragments: 8 coalesced 16B loads ----
        f16x8 k0[4], k1[4];
        #pragma unroll
        for (int ks = 0; ks < 4; ++ks) {
            k0[ks] = *(const f16x8*)(Kt + ks * 512 + lane * 8);
            k1[ks] = *(const f16x8*)(Kt + 2048 + ks * 512 + lane * 8);
        }

        // ---- QK^T swapped: S^T[key][q] ----
        f32x16 s0 = {}, s1 = {};
        __builtin_amdgcn_s_setprio(1);
        #pragma unroll
        for (int ks = 0; ks < 4; ++ks) {
            s0 = __builtin_amdgcn_mfma_f32_32x32x16_f16(k0[ks], qf[ks], s0, 0, 0, 0);
            s1 = __builtin_amdgcn_mfma_f32_32x32x16_f16(k1[ks], qf[ks], s1, 0, 0, 0);
        }
        __builtin_amdgcn_s_setprio(0);

        // ---- V fragments (issue early; latency hides under softmax) ----
        f16x8 vf[8];
        #pragma unroll
        for (int g = 0; g < 8; ++g)
            vf[g] = *(const f16x8*)(Vt + g * 512 + lane * 8);

        // ---- online softmax (log2 domain), lane-local rows ----
        float pm01 = fmaxf(s0[0], s0[1]), pm23 = fmaxf(s0[2], s0[3]);
        #pragma unroll
        for (int r = 4; r < 16; r += 4) {
            pm01 = fmaxf(pm01, fmaxf(s0[r], s0[r + 1]));
            pm23 = fmaxf(pm23, fmaxf(s0[r + 2], s0[r + 3]));
        }
        #pragma unroll
        for (int r = 0; r < 16; r += 4) {
            pm01 = fmaxf(pm01, fmaxf(s1[r], s1[r + 1]));
            pm23 = fmaxf(pm23, fmaxf(s1[r + 2], s1[r + 3]));
        }
        float pm = fmaxf(pm01, pm23);
        pm = fmaxf(pm, __shfl_xor(pm, 32));

        if (!__all(pm <= m + 10.0f)) {      // defer-max
            float mn = fmaxf(m, pm);
            float rs = exp2f(m - mn);
            #pragma unroll
            for (int r = 0; r < 16; ++r) { o0[r] *= rs; o1[r] *= rs; }
            l *= rs;
            m = mn;
        }

        float su0 = 0.f, su1 = 0.f, su2 = 0.f, su3 = 0.f;
        #pragma unroll
        for (int r = 0; r < 16; r += 4) {
            s0[r]     = exp2f(s0[r]     - m); su0 += s0[r];
            s0[r + 1] = exp2f(s0[r + 1] - m); su1 += s0[r + 1];
            s0[r + 2] = exp2f(s0[r + 2] - m); su2 += s0[r + 2];
            s0[r + 3] = exp2f(s0[r + 3] - m); su3 += s0[r + 3];
        }
        #pragma unroll
        for (int r = 0; r < 16; r += 4) {
            s1[r]     = exp2f(s1[r]     - m); su0 += s1[r];
            s1[r + 1] = exp2f(s1[r + 1] - m); su1 += s1[r + 1];
            s1[r + 2] = exp2f(s1[r + 2] - m); su2 += s1[r + 2];
            s1[r + 3] = exp2f(s1[r + 3] - m); su3 += s1[r + 3];
        }
        l += (su0 + su1) + (su2 + su3);

        // ---- pack P to f16, redistribute across hi-halves ----
        unsigned int w[16], xw[16];
        #pragma unroll
        for (int i = 0; i < 8; ++i) {
            w[i]     = pk16(s0[2 * i], s0[2 * i + 1]);
            w[8 + i] = pk16(s1[2 * i], s1[2 * i + 1]);
        }
        #pragma unroll
        for (int i = 0; i < 16; ++i) xw[i] = __shfl_xor(w[i], 32);

        union PA { unsigned int u[4]; f16x8 v; };
        PA pa[4];
        #pragma unroll
        for (int ks = 0; ks < 4; ++ks) {
            int bse = (ks >> 1) * 8 + (ks & 1) * 4;
            pa[ks].u[0] = hi ? xw[bse + 2] : w[bse + 0];
            pa[ks].u[1] = hi ? xw[bse + 3] : w[bse + 1];
            pa[ks].u[2] = hi ? w[bse + 2]  : xw[bse + 0];
            pa[ks].u[3] = hi ? w[bse + 3]  : xw[bse + 1];
        }

        // ---- PV: O^T += V^T x P^T ----
        __builtin_amdgcn_s_setprio(1);
        #pragma unroll
        for (int ks = 0; ks < 4; ++ks) {
            o0 = __builtin_amdgcn_mfma_f32_32x32x16_f16(vf[ks],     pa[ks].v, o0, 0, 0, 0);
            o1 = __builtin_amdgcn_mfma_f32_32x32x16_f16(vf[4 + ks], pa[ks].v, o1, 0, 0, 0);
        }
        __builtin_amdgcn_s_setprio(0);
    }

    // ---- epilogue ----
    float lt = l + __shfl_xor(l, 32);
    float inv = 1.0f / lt;
    float* orow = Og + ((long)bh * S_ + q0 + lq) * 64;
    #pragma unroll
    for (int r = 0; r < 16; ++r) {
        int d0 = (r & 3) + 8 * (r >> 2) + 4 * hi;
        orow[d0]      = o0[r] * inv;
        orow[d0 + 32] = o1[r] * inv;
    }
}

extern "C" void kernel_launch(void* const* d_in, const int* in_sizes, int n_in,
                              void* d_out, int out_size, void* d_ws, size_t ws_size,
                              hipStream_t stream) {
    const float* query = (const float*)d_in[0];
    const float* key   = (const float*)d_in[1];
    const float* value = (const float*)d_in[2];
    const float* Wq    = (const float*)d_in[3];
    const float* bq    = (const float*)d_in[4];
    const float* Wk    = (const float*)d_in[5];
    const float* bk    = (const float*)d_in[6];
    const float* Wv    = (const float*)d_in[7];
    const float* bv    = (const float*)d_in[8];

    const size_t elems = (size_t)B_ * H_ * S_ * D_;
    f16* qf = (f16*)d_ws;
    f16* kf = qf + elems;
    f16* vf = kf + elems;

    proj_kernel<<<dim3(S_ / 64, B_ * H_, 3), 256, 0, stream>>>(
        query, key, value, Wq, bq, Wk, bk, Wv, bv, qf, kf, vf);

    attn_kernel<<<512, 256, 0, stream>>>(qf, kf, vf, (float*)d_out);
}